// Round 1
// baseline (457.848 us; speedup 1.0000x reference)
//
#include <hip/hip_runtime.h>

// Problem constants: x(N=64,T=96,F=32); Wq/Wk/Wv (F*ND=256, T=96, D=128) tiled;
// ND=8 heads, D=128. Output = concat( y (N,T,F)=196608 f32, att (F,F)=1024 f32 ).

#define SQKD 0.08838834764831845f  // 1/sqrt(128)

// ---------------------------------------------------------------------------
// K1: Q/K/V projection.  q[b,n,d] = sum_t x[n,t,f] * W[b,t,d] + bias[b,d]
// b = f*8+kh. blockIdx.x = b (256), blockIdx.y = {0:q,1:k,2:v}. 256 threads.
// x column f staged in LDS as A[t*65+n] (pad 65 -> conflict-free writes,
// compute reads are wave-broadcast).
// ---------------------------------------------------------------------------
__global__ __launch_bounds__(256) void k_qkv(
    const float* __restrict__ x,
    const float* __restrict__ Wq, const float* __restrict__ Wk, const float* __restrict__ Wv,
    const float* __restrict__ bq, const float* __restrict__ bk, const float* __restrict__ bv,
    float* __restrict__ Q, float* __restrict__ K, float* __restrict__ V)
{
    const int b = blockIdx.x;          // 0..255
    const int f = b >> 3;
    const int sel = blockIdx.y;
    const float* W  = (sel == 0) ? Wq : (sel == 1) ? Wk : Wv;
    const float* bi = (sel == 0) ? bq : (sel == 1) ? bk : bv;
    float* O        = (sel == 0) ? Q  : (sel == 1) ? K  : V;

    __shared__ float A[96 * 65];
    const int tid = threadIdx.x;
    // stage x[:, :, f]: flat e = n*96+t, global addr = e*32+f (strided; L2-cached)
    for (int e = tid; e < 64 * 96; e += 256) {
        int n = e / 96, t = e - n * 96;
        A[t * 65 + n] = x[e * 32 + f];
    }
    __syncthreads();

    const int d  = tid & 127;
    const int n0 = tid >> 7;           // 0 or 1
    const float* Wb = W + b * (96 * 128);

    float acc[32];
#pragma unroll
    for (int i = 0; i < 32; ++i) acc[i] = 0.f;

    for (int t = 0; t < 96; ++t) {
        float w = Wb[t * 128 + d];     // coalesced
#pragma unroll
        for (int i = 0; i < 32; ++i)
            acc[i] += A[t * 65 + n0 + 2 * i] * w;   // LDS broadcast
    }

    float bb = bi[b * 128 + d];
    float* Ob = O + b * 8192;
#pragma unroll
    for (int i = 0; i < 32; ++i)
        Ob[(n0 + 2 * i) * 128 + d] = acc[i] + bb;   // coalesced
}

// ---------------------------------------------------------------------------
// K2 (hot): for each (f,g): S_k = (Q[f,k] * scale) @ K[g,k]^T  (64x64, kept in
// registers), fused contraction  H[f,g,e] += sum_{n,m} S_k[n,m]*w1[e,k,n,m].
// 1024 blocks (f*32+g), 256 threads, 4x4 S-tile per thread.
// LDS: q/k tiles 64x128 f32 each, XOR-swizzled (bank-conflict-free), 64 KB.
// ---------------------------------------------------------------------------
__global__ __launch_bounds__(256) void k_scores(
    const float* __restrict__ Q, const float* __restrict__ Kp,
    const float* __restrict__ w1, float* __restrict__ H)
{
    const int f = blockIdx.x >> 5, g = blockIdx.x & 31;
    __shared__ float q_lds[8192];
    __shared__ float k_lds[8192];
    const int tid = threadIdx.x;

    const int n0 = (tid >> 4) << 2;    // 0..60 step 4
    const int m0 = (tid & 15) << 2;    // 0..60 step 4
    const int sq = ((n0 >> 2) & 7) << 2;   // swizzle keys (const per thread)
    const int sk = ((m0 >> 2) & 7) << 2;

    float he[8];
#pragma unroll
    for (int e = 0; e < 8; ++e) he[e] = 0.f;

    for (int kh = 0; kh < 8; ++kh) {
        __syncthreads();               // guard LDS overwrite
        const float4* qg4 = (const float4*)(Q  + ((f << 3) + kh) * 8192);
        const float4* kg4 = (const float4*)(Kp + ((g << 3) + kh) * 8192);
        for (int e4 = tid; e4 < 2048; e4 += 256) {
            int n  = e4 >> 5;
            int d4 = (e4 & 31) << 2;
            int s  = ((n >> 2) & 7) << 2;
            float4 qv = qg4[e4];
            qv.x *= SQKD; qv.y *= SQKD; qv.z *= SQKD; qv.w *= SQKD;
            *(float4*)(q_lds + n * 128 + (d4 ^ s)) = qv;
            *(float4*)(k_lds + n * 128 + (d4 ^ s)) = kg4[e4];
        }
        __syncthreads();

        float acc[4][4];
#pragma unroll
        for (int i = 0; i < 4; ++i)
#pragma unroll
            for (int j = 0; j < 4; ++j) acc[i][j] = 0.f;

        const float* qb = q_lds + n0 * 128;
        const float* kb = k_lds + m0 * 128;
        for (int d = 0; d < 128; ++d) {
            const int dq = d ^ sq, dk = d ^ sk;
            float qa[4], kv[4];
#pragma unroll
            for (int i = 0; i < 4; ++i) qa[i] = qb[i * 128 + dq];
#pragma unroll
            for (int j = 0; j < 4; ++j) kv[j] = kb[j * 128 + dk];
#pragma unroll
            for (int i = 0; i < 4; ++i)
#pragma unroll
                for (int j = 0; j < 4; ++j) acc[i][j] += qa[i] * kv[j];
        }

        // fused w1 contraction: he[e] += sum_{i,j} S[n0+i][m0+j]*w1[e,kh,n,m]
        const float* wk = w1 + (kh << 12);
#pragma unroll
        for (int e = 0; e < 8; ++e) {
            const float* we = wk + (e << 15);
            float s = 0.f;
#pragma unroll
            for (int i = 0; i < 4; ++i) {
                float4 w = *(const float4*)(we + (n0 + i) * 64 + m0);
                s += acc[i][0] * w.x + acc[i][1] * w.y + acc[i][2] * w.z + acc[i][3] * w.w;
            }
            he[e] += s;
        }
    }

    // block reduction of he[8] over 256 threads
    __syncthreads();                   // LDS free for reuse
#pragma unroll
    for (int e = 0; e < 8; ++e)
        for (int off = 32; off > 0; off >>= 1)
            he[e] += __shfl_down(he[e], off);
    if ((tid & 63) == 0) {
        const int wid = tid >> 6;
#pragma unroll
        for (int e = 0; e < 8; ++e) q_lds[wid * 8 + e] = he[e];
    }
    __syncthreads();
    if (tid < 8)
        H[blockIdx.x * 8 + tid] =
            q_lds[tid] + q_lds[8 + tid] + q_lds[16 + tid] + q_lds[24 + tid];
}

// ---------------------------------------------------------------------------
// K3: logits = relu(H + b1) @ w2 + b2 ; att = softmax over g. 1 block.
// ---------------------------------------------------------------------------
__global__ void k_soft(const float* __restrict__ H, const float* __restrict__ b1,
                       const float* __restrict__ w2, const float* __restrict__ b2,
                       float* __restrict__ att)
{
    __shared__ float lg[1024];
    const int tid = threadIdx.x;       // 1024
    {
        float s = b2[0];
        const float* h = H + tid * 8;
#pragma unroll
        for (int e = 0; e < 8; ++e) s += fmaxf(h[e] + b1[e], 0.f) * w2[e];
        lg[tid] = s;
    }
    __syncthreads();
    if (tid < 32) {                    // tid = f, softmax over g
        float mx = -1e30f;
        for (int g2 = 0; g2 < 32; ++g2) mx = fmaxf(mx, lg[tid * 32 + g2]);
        float sum = 0.f;
        for (int g2 = 0; g2 < 32; ++g2) sum += expf(lg[tid * 32 + g2] - mx);
        float inv = 1.f / sum;
        for (int g2 = 0; g2 < 32; ++g2) att[tid * 32 + g2] = expf(lg[tid * 32 + g2] - mx) * inv;
    }
}

// ---------------------------------------------------------------------------
// K0: transpose w3 (128 x 1024) -> w3t (1024 x 128) so K5 reads coalesced.
// ---------------------------------------------------------------------------
__global__ __launch_bounds__(256) void k_tr(const float* __restrict__ w3,
                                            float* __restrict__ w3t)
{
    __shared__ float tile[32][33];
    const int it = blockIdx.x;         // 0..31
    const int dt = blockIdx.y;         // 0..3
    const int tx = threadIdx.x & 31, ty = threadIdx.x >> 5;  // 32x8
#pragma unroll
    for (int k2 = 0; k2 < 4; ++k2)
        tile[ty + k2 * 8][tx] = w3[(dt * 32 + ty + k2 * 8) * 1024 + it * 32 + tx];
    __syncthreads();
#pragma unroll
    for (int k2 = 0; k2 < 4; ++k2)
        w3t[(it * 32 + ty + k2 * 8) * 128 + dt * 32 + tx] = tile[tx][ty + k2 * 8];
}

// ---------------------------------------------------------------------------
// K4: bfull[f,kh,n,d] = sum_j att[f,j] * V[j,kh,n,d].  V read once (coalesced).
// 256 blocks x 256 threads; thread owns one column c, accumulates 32 f's.
// ---------------------------------------------------------------------------
__global__ __launch_bounds__(256) void k_bmix(const float* __restrict__ V,
                                              const float* __restrict__ att,
                                              float* __restrict__ bfull)
{
    __shared__ float a_s[1024];
    const int tid = threadIdx.x;
    for (int i = tid; i < 1024; i += 256) a_s[i] = att[i];
    __syncthreads();
    const int c = blockIdx.x * 256 + tid;   // 0..65535 over (kh,n,d)
    float acc[32];
#pragma unroll
    for (int f2 = 0; f2 < 32; ++f2) acc[f2] = 0.f;
    for (int j = 0; j < 32; ++j) {
        float v = V[j * 65536 + c];
#pragma unroll
        for (int f2 = 0; f2 < 32; ++f2) acc[f2] += a_s[(f2 << 5) + j] * v;
    }
#pragma unroll
    for (int f2 = 0; f2 < 32; ++f2) bfull[f2 * 65536 + c] = acc[f2];
}

// ---------------------------------------------------------------------------
// K5: per (f, 4-n tile): y1 = relu(bvec @ w3t + b3); y = y1 @ w4^T + b4;
// out[n,t,f] = y[t].  512 blocks x 128 threads.
// bvec[i = d*8+kh] = bfull[f,kh,n,d]  (reshape per reference).
// ---------------------------------------------------------------------------
__global__ __launch_bounds__(128) void k_out2(
    const float* __restrict__ bfull, const float* __restrict__ w3t,
    const float* __restrict__ b3, const float* __restrict__ w4,
    const float* __restrict__ b4, float* __restrict__ out)
{
    const int f = blockIdx.x >> 4, nt = blockIdx.x & 15;
    __shared__ float bv[4][1024];
    __shared__ float y1[4][128];
    const int tid = threadIdx.x;       // 128

#pragma unroll
    for (int ni = 0; ni < 4; ++ni) {
        const int n = nt * 4 + ni;
        for (int i2 = tid; i2 < 1024; i2 += 128) {
            int kh = i2 >> 7, d = i2 & 127;
            bv[ni][d * 8 + kh] = bfull[((f * 8 + kh) * 64 + n) * 128 + d];
        }
    }
    __syncthreads();

    {   // y1: thread = dout
        float acc[4];
        const float bias = b3[tid];
#pragma unroll
        for (int ni = 0; ni < 4; ++ni) acc[ni] = bias;
        for (int i = 0; i < 1024; ++i) {
            float w = w3t[i * 128 + tid];   // coalesced
#pragma unroll
            for (int ni = 0; ni < 4; ++ni) acc[ni] += bv[ni][i] * w;  // broadcast
        }
#pragma unroll
        for (int ni = 0; ni < 4; ++ni) y1[ni][tid] = fmaxf(acc[ni], 0.f);
    }
    __syncthreads();

    if (tid < 96) {                    // thread = t
        const int t = tid;
        const float bias = b4[t];
#pragma unroll
        for (int ni = 0; ni < 4; ++ni) {
            const int n = nt * 4 + ni;
            float s = bias;
            for (int d2 = 0; d2 < 128; ++d2)
                s += y1[ni][d2] * w4[t * 128 + d2];  // L1-resident rows
            out[(n * 96 + t) * 32 + f] = s;
        }
    }
}

// ---------------------------------------------------------------------------
extern "C" void kernel_launch(void* const* d_in, const int* in_sizes, int n_in,
                              void* d_out, int out_size, void* d_ws, size_t ws_size,
                              hipStream_t stream)
{
    const float* x  = (const float*)d_in[0];
    const float* Wq = (const float*)d_in[1];
    const float* Wk = (const float*)d_in[2];
    const float* Wv = (const float*)d_in[3];
    const float* bq = (const float*)d_in[4];
    const float* bk = (const float*)d_in[5];
    const float* bv = (const float*)d_in[6];
    const float* w1 = (const float*)d_in[7];
    const float* b1 = (const float*)d_in[8];
    const float* w2 = (const float*)d_in[9];
    const float* b2 = (const float*)d_in[10];
    const float* w3 = (const float*)d_in[11];
    const float* b3 = (const float*)d_in[12];
    const float* w4 = (const float*)d_in[13];
    const float* b4 = (const float*)d_in[14];

    float* out = (float*)d_out;
    float* ws  = (float*)d_ws;
    float* Qb  = ws;                  // 2097152 f32
    float* Kb  = ws + 2097152;        // 2097152 f32
    float* Vb  = ws + 4194304;        // 2097152 f32
    float* Hb  = ws + 6291456;        // 8192 f32   (total ws: 25.2 MB)
    float* w3t   = ws;                // overlays Q (dead after k_scores)
    float* bfull = ws + 2097152;      // overlays K (dead after k_scores)
    float* att = out + 196608;        // second output, also consumed by k_bmix

    k_qkv  <<<dim3(256, 3), 256, 0, stream>>>(x, Wq, Wk, Wv, bq, bk, bv, Qb, Kb, Vb);
    k_scores<<<1024, 256, 0, stream>>>(Qb, Kb, w1, Hb);
    k_soft <<<1, 1024, 0, stream>>>(Hb, b1, w2, b2, att);
    k_tr   <<<dim3(32, 4), 256, 0, stream>>>(w3, w3t);
    k_bmix <<<256, 256, 0, stream>>>(Vb, att, bfull);
    k_out2 <<<512, 128, 0, stream>>>(bfull, w3t, b3, w4, b4, out);
}

// Round 2
// 293.734 us; speedup vs baseline: 1.5587x; 1.5587x over previous
//
#include <hip/hip_runtime.h>

// N=64, T=96, F=32, ND=8, D=128. Output = concat( y (N,T,F)=196608 f32, att (F,F)=1024 f32 ).
#define SQKD 0.08838834764831845f  // 1/sqrt(128)

typedef __attribute__((ext_vector_type(8))) short short8;   // 8 bf16 = 4 VGPRs (MFMA A/B frag)
typedef __attribute__((ext_vector_type(4))) float f32x4;    // MFMA C/D frag

// Split fp32 into bf16 hi + bf16 lo (RNE): f ~= hi + lo with ~2^-17 rel error.
__device__ __forceinline__ void bf16split(float f, unsigned short& hi, unsigned short& lo) {
    unsigned u = __float_as_uint(f);
    unsigned r = (u + 0x7FFFu + ((u >> 16) & 1u)) >> 16;
    hi = (unsigned short)r;
    float fl = f - __uint_as_float(r << 16);
    unsigned u2 = __float_as_uint(fl);
    unsigned r2 = (u2 + 0x7FFFu + ((u2 >> 16) & 1u)) >> 16;
    lo = (unsigned short)r2;
}

// ---------------------------------------------------------------------------
// K1: Q/K/V projection. q[b,n,d] = sum_t x[n,t,f]*W[b,t,d] + bias.
// Q/K written as split bf16 hi/lo (Q pre-scaled by 1/sqrt(D)); V stays fp32.
// ---------------------------------------------------------------------------
__global__ __launch_bounds__(256) void k_qkv(
    const float* __restrict__ x,
    const float* __restrict__ Wq, const float* __restrict__ Wk, const float* __restrict__ Wv,
    const float* __restrict__ bq, const float* __restrict__ bk, const float* __restrict__ bv,
    unsigned short* __restrict__ qhi, unsigned short* __restrict__ qlo,
    unsigned short* __restrict__ khi, unsigned short* __restrict__ klo,
    float* __restrict__ V)
{
    const int b = blockIdx.x;          // 0..255
    const int f = b >> 3;
    const int sel = blockIdx.y;        // 0:q 1:k 2:v
    const float* W  = (sel == 0) ? Wq : (sel == 1) ? Wk : Wv;
    const float* bi = (sel == 0) ? bq : (sel == 1) ? bk : bv;

    __shared__ float A[96 * 65];
    const int tid = threadIdx.x;
    for (int e = tid; e < 64 * 96; e += 256) {
        int n = e / 96, t = e - n * 96;
        A[t * 65 + n] = x[e * 32 + f];
    }
    __syncthreads();

    const int d  = tid & 127;
    const int n0 = tid >> 7;           // 0 or 1
    const float* Wb = W + b * (96 * 128);

    float acc[32];
#pragma unroll
    for (int i = 0; i < 32; ++i) acc[i] = 0.f;
    for (int t = 0; t < 96; ++t) {
        float w = Wb[t * 128 + d];
#pragma unroll
        for (int i = 0; i < 32; ++i)
            acc[i] += A[t * 65 + n0 + 2 * i] * w;
    }
    float bb = bi[b * 128 + d];

    if (sel == 2) {
        float* Ob = V + b * 8192;
#pragma unroll
        for (int i = 0; i < 32; ++i)
            Ob[(n0 + 2 * i) * 128 + d] = acc[i] + bb;
    } else {
        unsigned short* ohi = sel ? khi : qhi;
        unsigned short* olo = sel ? klo : qlo;
        const float scale = sel ? 1.0f : SQKD;
#pragma unroll
        for (int i = 0; i < 32; ++i) {
            float v = (acc[i] + bb) * scale;
            unsigned short h, l;
            bf16split(v, h, l);
            int idx = b * 8192 + (n0 + 2 * i) * 128 + d;
            ohi[idx] = h; olo[idx] = l;
        }
    }
}

// ---------------------------------------------------------------------------
// K2 (hot): per block: 2 f x 1 g. For each kh: S = (Q*scale) @ K^T (64x64) via
// bf16 MFMA with hi/lo split (3 terms -> fp32-accurate), then cooperative
// contraction he[pair][e] += sum_p S[p]*w1[e,kh,p] with coalesced w1 reads.
// 512 blocks x 256 threads. LDS 62 KB -> 2 blocks/CU.
// Wave layout: wid -> (pf = wid>>1 : which f, wsub = wid&1 : n-half 0..31/32..63).
// D chunked x32 (1 mfma k-step per chunk). LDS rows padded to 40 ushort.
// ---------------------------------------------------------------------------
__global__ __launch_bounds__(256, 2) void k_scores(
    const unsigned short* __restrict__ qhi, const unsigned short* __restrict__ qlo,
    const unsigned short* __restrict__ khi, const unsigned short* __restrict__ klo,
    const float* __restrict__ w1, float* __restrict__ H)
{
    __shared__ __align__(16) unsigned short sQhi[2 * 64 * 40];  // 10 KB
    __shared__ __align__(16) unsigned short sQlo[2 * 64 * 40];
    __shared__ __align__(16) unsigned short sKhi[64 * 40];      // 5 KB
    __shared__ __align__(16) unsigned short sKlo[64 * 40];
    __shared__ __align__(16) float sS[2 * 4096];                // 32 KB

    const int tid  = threadIdx.x;
    const int lane = tid & 63, wid = tid >> 6;
    const int quad = lane >> 4, col = lane & 15;
    const int f0 = (blockIdx.x >> 5) << 1;     // 0..30 step 2
    const int g  = blockIdx.x & 31;
    const int pf = wid >> 1;                   // wave's f (0/1)
    const int wsub = wid & 1;                  // wave's n-half

    float he[2][8];
#pragma unroll
    for (int w = 0; w < 2; ++w)
#pragma unroll
        for (int e = 0; e < 8; ++e) he[w][e] = 0.f;

    for (int kh = 0; kh < 8; ++kh) {
        f32x4 acc[2][4];
#pragma unroll
        for (int ti = 0; ti < 2; ++ti)
#pragma unroll
            for (int tj = 0; tj < 4; ++tj)
#pragma unroll
                for (int r = 0; r < 4; ++r) acc[ti][tj][r] = 0.f;

        for (int ch = 0; ch < 4; ++ch) {       // d in [ch*32, ch*32+32)
            __syncthreads();
            // stage: 1536 granule-copies of 16B (Q:1024, K:512), 6 per thread
#pragma unroll
            for (int it = 0; it < 6; ++it) {
                const int r  = tid >> 2;       // 0..63
                const int gg = tid & 3;        // granule in chunk
                const unsigned short* src;
                unsigned short* dst;
                long goff; int doff;
                if (it < 4) {                  // Q: hl = it>>1, fi = it&1
                    const int hl = it >> 1, fi = it & 1;
                    src = hl ? qlo : qhi;
                    dst = hl ? sQlo : sQhi;
                    goff = (long)((f0 + fi) * 8 + kh) * 8192 + r * 128 + ch * 32 + gg * 8;
                    doff = (fi * 64 + r) * 40 + gg * 8;
                } else {                       // K: hl = it&1
                    const int hl = it & 1;
                    src = hl ? klo : khi;
                    dst = hl ? sKlo : sKhi;
                    goff = (long)(g * 8 + kh) * 8192 + r * 128 + ch * 32 + gg * 8;
                    doff = r * 40 + gg * 8;
                }
                *(short8*)(dst + doff) = *(const short8*)(src + goff);
            }
            __syncthreads();

            // MFMA: this wave's 2 n-tiles x 4 m-tiles, 3 split terms
            short8 ah[2], al[2], bh[4], bl[4];
#pragma unroll
            for (int t = 0; t < 2; ++t) {
                const int r = (wsub * 2 + t) * 16 + col;
                const int off = (pf * 64 + r) * 40 + quad * 8;
                ah[t] = *(const short8*)(sQhi + off);
                al[t] = *(const short8*)(sQlo + off);
            }
#pragma unroll
            for (int t = 0; t < 4; ++t) {
                const int off = (t * 16 + col) * 40 + quad * 8;
                bh[t] = *(const short8*)(sKhi + off);
                bl[t] = *(const short8*)(sKlo + off);
            }
#pragma unroll
            for (int ti = 0; ti < 2; ++ti)
#pragma unroll
                for (int tj = 0; tj < 4; ++tj) {
                    acc[ti][tj] = __builtin_amdgcn_mfma_f32_16x16x32_bf16(ah[ti], bh[tj], acc[ti][tj], 0, 0, 0);
                    acc[ti][tj] = __builtin_amdgcn_mfma_f32_16x16x32_bf16(al[ti], bh[tj], acc[ti][tj], 0, 0, 0);
                    acc[ti][tj] = __builtin_amdgcn_mfma_f32_16x16x32_bf16(ah[ti], bl[tj], acc[ti][tj], 0, 0, 0);
                }
        }

        // write S to LDS (C-layout: row n = tile*16+quad*4+reg, col m = tj*16+col)
        // m swizzled by XOR 16*((n>>2)&1) -> 2-way write conflicts (free)
        float* Sw = sS + pf * 4096;
#pragma unroll
        for (int ti = 0; ti < 2; ++ti)
#pragma unroll
            for (int tj = 0; tj < 4; ++tj)
#pragma unroll
                for (int r = 0; r < 4; ++r) {
                    const int n = (wsub * 2 + ti) * 16 + quad * 4 + r;
                    const int m = tj * 16 + col;
                    Sw[n * 64 + (m ^ (((n >> 2) & 1) << 4))] = acc[ti][tj][r];
                }
        __syncthreads();

        // cooperative contraction: he[pf][e] += sum_p S[pf][p] * w1[e, kh*4096+p]
        const float* w1k = w1 + kh * 4096;
#pragma unroll
        for (int i = 0; i < 4; ++i) {
            const int p = i * 1024 + tid * 4;
            const int n = p >> 6;
            const int mm = (p & 63) ^ (((n >> 2) & 1) << 4);
            const float* sp = sS + n * 64 + mm;
            f32x4 s0 = *(const f32x4*)(sp);
            f32x4 s1 = *(const f32x4*)(sp + 4096);
#pragma unroll
            for (int e = 0; e < 8; ++e) {
                f32x4 w = *(const f32x4*)(w1k + e * 32768 + p);
                he[0][e] += s0.x * w.x + s0.y * w.y + s0.z * w.z + s0.w * w.w;
                he[1][e] += s1.x * w.x + s1.y * w.y + s1.z * w.z + s1.w * w.w;
            }
        }
    }

    // block-reduce he over 256 threads
    __syncthreads();                    // all contraction reads of sS done
    float* red = sS;
#pragma unroll
    for (int w = 0; w < 2; ++w)
#pragma unroll
        for (int e = 0; e < 8; ++e) {
            float v = he[w][e];
            v += __shfl_down(v, 32); v += __shfl_down(v, 16); v += __shfl_down(v, 8);
            v += __shfl_down(v, 4);  v += __shfl_down(v, 2);  v += __shfl_down(v, 1);
            if (lane == 0) red[wid * 16 + w * 8 + e] = v;
        }
    __syncthreads();
    if (tid < 16) {
        const int w = tid >> 3, e = tid & 7;
        float v = red[tid] + red[16 + tid] + red[32 + tid] + red[48 + tid];
        H[((f0 + w) * 32 + g) * 8 + e] = v;
    }
}

// ---------------------------------------------------------------------------
// K3: logits = relu(H + b1) @ w2 + b2 ; att = softmax over g. 1 block.
// ---------------------------------------------------------------------------
__global__ void k_soft(const float* __restrict__ H, const float* __restrict__ b1,
                       const float* __restrict__ w2, const float* __restrict__ b2,
                       float* __restrict__ att)
{
    __shared__ float lg[1024];
    const int tid = threadIdx.x;       // 1024
    {
        float s = b2[0];
        const float* h = H + tid * 8;
#pragma unroll
        for (int e = 0; e < 8; ++e) s += fmaxf(h[e] + b1[e], 0.f) * w2[e];
        lg[tid] = s;
    }
    __syncthreads();
    if (tid < 32) {
        float mx = -1e30f;
        for (int g2 = 0; g2 < 32; ++g2) mx = fmaxf(mx, lg[tid * 32 + g2]);
        float sum = 0.f;
        for (int g2 = 0; g2 < 32; ++g2) sum += expf(lg[tid * 32 + g2] - mx);
        float inv = 1.f / sum;
        for (int g2 = 0; g2 < 32; ++g2) att[tid * 32 + g2] = expf(lg[tid * 32 + g2] - mx) * inv;
    }
}

// ---------------------------------------------------------------------------
// K0: transpose w3 (128 x 1024) -> w3t (1024 x 128).
// ---------------------------------------------------------------------------
__global__ __launch_bounds__(256) void k_tr(const float* __restrict__ w3,
                                            float* __restrict__ w3t)
{
    __shared__ float tile[32][33];
    const int it = blockIdx.x;         // 0..31
    const int dt = blockIdx.y;         // 0..3
    const int tx = threadIdx.x & 31, ty = threadIdx.x >> 5;
#pragma unroll
    for (int k2 = 0; k2 < 4; ++k2)
        tile[ty + k2 * 8][tx] = w3[(dt * 32 + ty + k2 * 8) * 1024 + it * 32 + tx];
    __syncthreads();
#pragma unroll
    for (int k2 = 0; k2 < 4; ++k2)
        w3t[(it * 32 + ty + k2 * 8) * 128 + dt * 32 + tx] = tile[tx][ty + k2 * 8];
}

// ---------------------------------------------------------------------------
// K4: bfull[f,kh,n,d] = sum_j att[f,j] * V[j,kh,n,d].
// ---------------------------------------------------------------------------
__global__ __launch_bounds__(256) void k_bmix(const float* __restrict__ V,
                                              const float* __restrict__ att,
                                              float* __restrict__ bfull)
{
    __shared__ float a_s[1024];
    const int tid = threadIdx.x;
    for (int i = tid; i < 1024; i += 256) a_s[i] = att[i];
    __syncthreads();
    const int c = blockIdx.x * 256 + tid;
    float acc[32];
#pragma unroll
    for (int f2 = 0; f2 < 32; ++f2) acc[f2] = 0.f;
    for (int j = 0; j < 32; ++j) {
        float v = V[j * 65536 + c];
#pragma unroll
        for (int f2 = 0; f2 < 32; ++f2) acc[f2] += a_s[(f2 << 5) + j] * v;
    }
#pragma unroll
    for (int f2 = 0; f2 < 32; ++f2) bfull[f2 * 65536 + c] = acc[f2];
}

// ---------------------------------------------------------------------------
// K5: per (f, 4-n tile): y1 = relu(bvec @ w3t + b3); y = y1 @ w4^T + b4.
// ---------------------------------------------------------------------------
__global__ __launch_bounds__(128) void k_out2(
    const float* __restrict__ bfull, const float* __restrict__ w3t,
    const float* __restrict__ b3, const float* __restrict__ w4,
    const float* __restrict__ b4, float* __restrict__ out)
{
    const int f = blockIdx.x >> 4, nt = blockIdx.x & 15;
    __shared__ float bv[4][1024];
    __shared__ float y1[4][128];
    const int tid = threadIdx.x;       // 128

#pragma unroll
    for (int ni = 0; ni < 4; ++ni) {
        const int n = nt * 4 + ni;
        for (int i2 = tid; i2 < 1024; i2 += 128) {
            int kh = i2 >> 7, d = i2 & 127;
            bv[ni][d * 8 + kh] = bfull[((f * 8 + kh) * 64 + n) * 128 + d];
        }
    }
    __syncthreads();

    {
        float acc[4];
        const float bias = b3[tid];
#pragma unroll
        for (int ni = 0; ni < 4; ++ni) acc[ni] = bias;
        for (int i = 0; i < 1024; ++i) {
            float w = w3t[i * 128 + tid];
#pragma unroll
            for (int ni = 0; ni < 4; ++ni) acc[ni] += bv[ni][i] * w;
        }
#pragma unroll
        for (int ni = 0; ni < 4; ++ni) y1[ni][tid] = fmaxf(acc[ni], 0.f);
    }
    __syncthreads();

    if (tid < 96) {
        const int t = tid;
        const float bias = b4[t];
#pragma unroll
        for (int ni = 0; ni < 4; ++ni) {
            const int n = nt * 4 + ni;
            float s = bias;
            for (int d2 = 0; d2 < 128; ++d2)
                s += y1[ni][d2] * w4[t * 128 + d2];
            out[(n * 96 + t) * 32 + f] = s;
        }
    }
}

// ---------------------------------------------------------------------------
extern "C" void kernel_launch(void* const* d_in, const int* in_sizes, int n_in,
                              void* d_out, int out_size, void* d_ws, size_t ws_size,
                              hipStream_t stream)
{
    const float* x  = (const float*)d_in[0];
    const float* Wq = (const float*)d_in[1];
    const float* Wk = (const float*)d_in[2];
    const float* Wv = (const float*)d_in[3];
    const float* bq = (const float*)d_in[4];
    const float* bk = (const float*)d_in[5];
    const float* bv = (const float*)d_in[6];
    const float* w1 = (const float*)d_in[7];
    const float* b1 = (const float*)d_in[8];
    const float* w2 = (const float*)d_in[9];
    const float* b2 = (const float*)d_in[10];
    const float* w3 = (const float*)d_in[11];
    const float* b3 = (const float*)d_in[12];
    const float* w4 = (const float*)d_in[13];
    const float* b4 = (const float*)d_in[14];

    float* out = (float*)d_out;
    unsigned short* qhi = (unsigned short*)d_ws;      // 4 MB
    unsigned short* qlo = qhi + 2097152;              // 4 MB
    unsigned short* khi = qlo + 2097152;              // 4 MB
    unsigned short* klo = khi + 2097152;              // 4 MB
    float* Vb = (float*)(klo + 2097152);              // 8 MB  (at 16 MB)
    float* Hb = Vb + 2097152;                         // 32 KB (at 24 MB)
    float* w3t   = (float*)d_ws;                      // overlays qhi (dead after k_scores)
    float* bfull = (float*)khi;                       // overlays khi/klo (dead after k_scores)
    float* att = out + 196608;

    k_qkv   <<<dim3(256, 3), 256, 0, stream>>>(x, Wq, Wk, Wv, bq, bk, bv,
                                               qhi, qlo, khi, klo, Vb);
    k_scores<<<512, 256, 0, stream>>>(qhi, qlo, khi, klo, w1, Hb);
    k_soft  <<<1, 1024, 0, stream>>>(Hb, b1, w2, b2, att);
    k_tr    <<<dim3(32, 4), 256, 0, stream>>>(w3, w3t);
    k_bmix  <<<256, 256, 0, stream>>>(Vb, att, bfull);
    k_out2  <<<512, 128, 0, stream>>>(bfull, w3t, b3, w4, b4, out);
}

// Round 3
// 228.104 us; speedup vs baseline: 2.0072x; 1.2877x over previous
//
#include <hip/hip_runtime.h>

// N=64, T=96, F=32, ND=8, D=128. Output = concat( y (N,T,F)=196608 f32, att (F,F)=1024 f32 ).
#define SQKD 0.08838834764831845f  // 1/sqrt(128)

typedef __attribute__((ext_vector_type(8))) short short8;   // 8 bf16 = 4 VGPRs (MFMA A/B frag)
typedef __attribute__((ext_vector_type(4))) float f32x4;    // MFMA C/D frag

// Split fp32 into bf16 hi + bf16 lo (RNE): f ~= hi + lo with ~2^-16 rel error.
__device__ __forceinline__ void bf16split(float f, unsigned short& hi, unsigned short& lo) {
    unsigned u = __float_as_uint(f);
    unsigned r = (u + 0x7FFFu + ((u >> 16) & 1u)) >> 16;
    hi = (unsigned short)r;
    float fl = f - __uint_as_float(r << 16);
    unsigned u2 = __float_as_uint(fl);
    unsigned r2 = (u2 + 0x7FFFu + ((u2 >> 16) & 1u)) >> 16;
    lo = (unsigned short)r2;
}

// ---------------------------------------------------------------------------
// K0 prep: exploit W tiling (only ND=8 distinct head matrices per sel!).
//  blocks 0..63  (n): split x -> Ahi/Alo[(f*64+n)][t]   (2048 x 96 bf16 pair)
//  blocks 64..87 (sel,kh): split+transpose Wbase -> Wth/Wtl[(w*128+d)][t]
//                (Wq pre-scaled by 1/sqrt(D))
// ---------------------------------------------------------------------------
__global__ __launch_bounds__(256) void k_prep(
    const float* __restrict__ x, const float* __restrict__ Wq,
    const float* __restrict__ Wk, const float* __restrict__ Wv,
    unsigned short* __restrict__ Ahi, unsigned short* __restrict__ Alo,
    unsigned short* __restrict__ Wth, unsigned short* __restrict__ Wtl)
{
    __shared__ float s_ws[96 * 129];
    const int tid = threadIdx.x;
    const int bid = blockIdx.x;
    if (bid < 64) {                      // x-split, block = n
        const int n = bid;
        for (int e = tid; e < 3072; e += 256)        // e = t*32+f, coalesced read
            s_ws[(e >> 5) * 33 + (e & 31)] = x[n * 3072 + e];
        __syncthreads();
        const int f = tid >> 3, tg = tid & 7;
#pragma unroll
        for (int j = 0; j < 12; ++j) {
            const int t = tg * 12 + j;
            float v = s_ws[t * 33 + f];
            unsigned short h, l; bf16split(v, h, l);
            Ahi[(f * 64 + n) * 96 + t] = h;
            Alo[(f * 64 + n) * 96 + t] = l;
        }
    } else {                             // W-split, block = (sel,kh)
        const int w = bid - 64;          // 0..23
        const int sel = w >> 3, kh = w & 7;
        const float* src = (sel == 0 ? Wq : sel == 1 ? Wk : Wv) + kh * 12288;
        for (int e = tid; e < 12288; e += 256)       // e = t*128+d, coalesced
            s_ws[(e >> 7) * 129 + (e & 127)] = src[e];
        __syncthreads();
        const int d = tid >> 1, th = tid & 1;
        const float sc = (sel == 0) ? SQKD : 1.0f;
#pragma unroll
        for (int j = 0; j < 48; ++j) {
            const int t = th * 48 + j;
            float v = s_ws[t * 129 + d] * sc;
            unsigned short h, l; bf16split(v, h, l);
            Wth[(w * 128 + d) * 96 + t] = h;
            Wtl[(w * 128 + d) * 96 + t] = l;
        }
    }
}

// ---------------------------------------------------------------------------
// K1: QKV via MFMA. grid (f=32, nh=2, b24=24: sel*8+kh). Per block:
// D[64n x 64d] = A[64 x 96] @ W[96 x 64], 3-term bf16 split = fp32-accurate.
// Q/K written pre-split hi/lo (Q already scaled via Wq); V written f32.
// ---------------------------------------------------------------------------
__global__ __launch_bounds__(256) void k_qkvg(
    const unsigned short* __restrict__ Ahi, const unsigned short* __restrict__ Alo,
    const unsigned short* __restrict__ Wth, const unsigned short* __restrict__ Wtl,
    const float* __restrict__ bq, const float* __restrict__ bk, const float* __restrict__ bv,
    unsigned short* __restrict__ qhi, unsigned short* __restrict__ qlo,
    unsigned short* __restrict__ khi, unsigned short* __restrict__ klo,
    float* __restrict__ V)
{
    __shared__ __align__(16) unsigned short sAh[64 * 96], sAl[64 * 96];
    __shared__ __align__(16) unsigned short sBh[64 * 96], sBl[64 * 96];
    const int tid = threadIdx.x;
    const int f = blockIdx.x, nh = blockIdx.y, b24 = blockIdx.z;
    const int sel = b24 >> 3, kh = b24 & 7;

    const unsigned short* gAh = Ahi + f * 6144;
    const unsigned short* gAl = Alo + f * 6144;
    const unsigned short* gBh = Wth + (b24 * 128 + nh * 64) * 96;
    const unsigned short* gBl = Wtl + (b24 * 128 + nh * 64) * 96;
#pragma unroll
    for (int it = 0; it < 3; ++it) {     // contiguous 16B-granule slab copies
        const int off = (it * 256 + tid) * 8;
        *(short8*)(sAh + off) = *(const short8*)(gAh + off);
        *(short8*)(sAl + off) = *(const short8*)(gAl + off);
        *(short8*)(sBh + off) = *(const short8*)(gBh + off);
        *(short8*)(sBl + off) = *(const short8*)(gBl + off);
    }
    __syncthreads();

    const int lane = tid & 63, wid = tid >> 6;
    const int quad = lane >> 4, col = lane & 15;
    f32x4 acc[4];
#pragma unroll
    for (int nt = 0; nt < 4; ++nt)
#pragma unroll
        for (int r = 0; r < 4; ++r) acc[nt][r] = 0.f;

#pragma unroll
    for (int ks = 0; ks < 3; ++ks) {
        const int ko = ks * 32 + quad * 8;
        short8 ah = *(const short8*)(sAh + (wid * 16 + col) * 96 + ko);
        short8 al = *(const short8*)(sAl + (wid * 16 + col) * 96 + ko);
#pragma unroll
        for (int nt = 0; nt < 4; ++nt) {
            short8 bh = *(const short8*)(sBh + (nt * 16 + col) * 96 + ko);
            short8 bl = *(const short8*)(sBl + (nt * 16 + col) * 96 + ko);
            acc[nt] = __builtin_amdgcn_mfma_f32_16x16x32_bf16(ah, bh, acc[nt], 0, 0, 0);
            acc[nt] = __builtin_amdgcn_mfma_f32_16x16x32_bf16(al, bh, acc[nt], 0, 0, 0);
            acc[nt] = __builtin_amdgcn_mfma_f32_16x16x32_bf16(ah, bl, acc[nt], 0, 0, 0);
        }
    }

    const int b = f * 8 + kh;
    const float* bias = sel == 0 ? bq : sel == 1 ? bk : bv;
    const float bsc = (sel == 0) ? SQKD : 1.0f;
#pragma unroll
    for (int nt = 0; nt < 4; ++nt) {
        const int d = nh * 64 + nt * 16 + col;
        const float bb = bias[b * 128 + d] * bsc;
#pragma unroll
        for (int r = 0; r < 4; ++r) {
            const int n = wid * 16 + quad * 4 + r;
            const float v = acc[nt][r] + bb;
            const int o = (b * 64 + n) * 128 + d;
            if (sel == 2) V[o] = v;
            else if (sel == 0) { unsigned short h, l; bf16split(v, h, l); qhi[o] = h; qlo[o] = l; }
            else               { unsigned short h, l; bf16split(v, h, l); khi[o] = h; klo[o] = l; }
        }
    }
}

// ---------------------------------------------------------------------------
// K2 (hot): per block 2f x 1g. S = Q@K^T via 3-term split MFMA; fused fp32
// w1 contraction. w1 loads for i=0,1 prefetched at kh-top so L2 latency
// overlaps the MFMA/staging phase.
// ---------------------------------------------------------------------------
__global__ __launch_bounds__(256, 2) void k_scores(
    const unsigned short* __restrict__ qhi, const unsigned short* __restrict__ qlo,
    const unsigned short* __restrict__ khi, const unsigned short* __restrict__ klo,
    const float* __restrict__ w1, float* __restrict__ H)
{
    __shared__ __align__(16) unsigned short sQhi[2 * 64 * 40];
    __shared__ __align__(16) unsigned short sQlo[2 * 64 * 40];
    __shared__ __align__(16) unsigned short sKhi[64 * 40];
    __shared__ __align__(16) unsigned short sKlo[64 * 40];
    __shared__ __align__(16) float sS[2 * 4096];

    const int tid  = threadIdx.x;
    const int lane = tid & 63, wid = tid >> 6;
    const int quad = lane >> 4, col = lane & 15;
    const int f0 = (blockIdx.x >> 5) << 1;
    const int g  = blockIdx.x & 31;
    const int pf = wid >> 1;
    const int wsub = wid & 1;

    float he[2][8];
#pragma unroll
    for (int w = 0; w < 2; ++w)
#pragma unroll
        for (int e = 0; e < 8; ++e) he[w][e] = 0.f;

    for (int kh = 0; kh < 8; ++kh) {
        const float* w1k = w1 + (kh << 12);
        // prefetch w1 for i=0,1 (64 VGPRs) — overlaps staging+MFMA below
        f32x4 wp[16];
#pragma unroll
        for (int ii = 0; ii < 2; ++ii)
#pragma unroll
            for (int e = 0; e < 8; ++e)
                wp[ii * 8 + e] = *(const f32x4*)(w1k + e * 32768 + ii * 1024 + tid * 4);

        f32x4 acc[2][4];
#pragma unroll
        for (int ti = 0; ti < 2; ++ti)
#pragma unroll
            for (int tj = 0; tj < 4; ++tj)
#pragma unroll
                for (int r = 0; r < 4; ++r) acc[ti][tj][r] = 0.f;

        for (int ch = 0; ch < 4; ++ch) {
            __syncthreads();
#pragma unroll
            for (int it = 0; it < 6; ++it) {
                const int r  = tid >> 2;
                const int gg = tid & 3;
                const unsigned short* src;
                unsigned short* dst;
                long goff; int doff;
                if (it < 4) {
                    const int hl = it >> 1, fi = it & 1;
                    src = hl ? qlo : qhi;
                    dst = hl ? sQlo : sQhi;
                    goff = (long)((f0 + fi) * 8 + kh) * 8192 + r * 128 + ch * 32 + gg * 8;
                    doff = (fi * 64 + r) * 40 + gg * 8;
                } else {
                    const int hl = it & 1;
                    src = hl ? klo : khi;
                    dst = hl ? sKlo : sKhi;
                    goff = (long)(g * 8 + kh) * 8192 + r * 128 + ch * 32 + gg * 8;
                    doff = r * 40 + gg * 8;
                }
                *(short8*)(dst + doff) = *(const short8*)(src + goff);
            }
            __syncthreads();

            short8 ah[2], al[2], bh[4], bl[4];
#pragma unroll
            for (int t = 0; t < 2; ++t) {
                const int r = (wsub * 2 + t) * 16 + col;
                const int off = (pf * 64 + r) * 40 + quad * 8;
                ah[t] = *(const short8*)(sQhi + off);
                al[t] = *(const short8*)(sQlo + off);
            }
#pragma unroll
            for (int t = 0; t < 4; ++t) {
                const int off = (t * 16 + col) * 40 + quad * 8;
                bh[t] = *(const short8*)(sKhi + off);
                bl[t] = *(const short8*)(sKlo + off);
            }
#pragma unroll
            for (int ti = 0; ti < 2; ++ti)
#pragma unroll
                for (int tj = 0; tj < 4; ++tj) {
                    acc[ti][tj] = __builtin_amdgcn_mfma_f32_16x16x32_bf16(ah[ti], bh[tj], acc[ti][tj], 0, 0, 0);
                    acc[ti][tj] = __builtin_amdgcn_mfma_f32_16x16x32_bf16(al[ti], bh[tj], acc[ti][tj], 0, 0, 0);
                    acc[ti][tj] = __builtin_amdgcn_mfma_f32_16x16x32_bf16(ah[ti], bl[tj], acc[ti][tj], 0, 0, 0);
                }
        }

        float* Sw = sS + pf * 4096;
#pragma unroll
        for (int ti = 0; ti < 2; ++ti)
#pragma unroll
            for (int tj = 0; tj < 4; ++tj)
#pragma unroll
                for (int r = 0; r < 4; ++r) {
                    const int n = (wsub * 2 + ti) * 16 + quad * 4 + r;
                    const int m = tj * 16 + col;
                    Sw[n * 64 + (m ^ (((n >> 2) & 1) << 4))] = acc[ti][tj][r];
                }
        __syncthreads();

#pragma unroll
        for (int i = 0; i < 4; ++i) {
            const int p = i * 1024 + tid * 4;
            const int n = p >> 6;
            const int mm = (p & 63) ^ (((n >> 2) & 1) << 4);
            const float* sp = sS + n * 64 + mm;
            f32x4 s0 = *(const f32x4*)(sp);
            f32x4 s1 = *(const f32x4*)(sp + 4096);
#pragma unroll
            for (int e = 0; e < 8; ++e) {
                f32x4 w = (i < 2) ? wp[i * 8 + e]
                                  : *(const f32x4*)(w1k + e * 32768 + p);
                he[0][e] += s0.x * w.x + s0.y * w.y + s0.z * w.z + s0.w * w.w;
                he[1][e] += s1.x * w.x + s1.y * w.y + s1.z * w.z + s1.w * w.w;
            }
        }
    }

    __syncthreads();
    float* red = sS;
#pragma unroll
    for (int w = 0; w < 2; ++w)
#pragma unroll
        for (int e = 0; e < 8; ++e) {
            float v = he[w][e];
            v += __shfl_down(v, 32); v += __shfl_down(v, 16); v += __shfl_down(v, 8);
            v += __shfl_down(v, 4);  v += __shfl_down(v, 2);  v += __shfl_down(v, 1);
            if (lane == 0) red[wid * 16 + w * 8 + e] = v;
        }
    __syncthreads();
    if (tid < 16) {
        const int w = tid >> 3, e = tid & 7;
        float v = red[tid] + red[16 + tid] + red[32 + tid] + red[48 + tid];
        H[((f0 + w) * 32 + g) * 8 + e] = v;
    }
}

// ---------------------------------------------------------------------------
// K3: logits = relu(H + b1) @ w2 + b2 ; att = softmax over g. 1 block.
// ---------------------------------------------------------------------------
__global__ void k_soft(const float* __restrict__ H, const float* __restrict__ b1,
                       const float* __restrict__ w2, const float* __restrict__ b2,
                       float* __restrict__ att)
{
    __shared__ float lg[1024];
    const int tid = threadIdx.x;       // 1024
    {
        float s = b2[0];
        const float* h = H + tid * 8;
#pragma unroll
        for (int e = 0; e < 8; ++e) s += fmaxf(h[e] + b1[e], 0.f) * w2[e];
        lg[tid] = s;
    }
    __syncthreads();
    if (tid < 32) {
        float mx = -1e30f;
        for (int g2 = 0; g2 < 32; ++g2) mx = fmaxf(mx, lg[tid * 32 + g2]);
        float sum = 0.f;
        for (int g2 = 0; g2 < 32; ++g2) sum += expf(lg[tid * 32 + g2] - mx);
        float inv = 1.f / sum;
        for (int g2 = 0; g2 < 32; ++g2) att[tid * 32 + g2] = expf(lg[tid * 32 + g2] - mx) * inv;
    }
}

// ---------------------------------------------------------------------------
// K4: bfull[f,kh,n,d] = sum_j att[f,j] * V[j,kh,n,d].
// 256 blocks x 256 threads; thread owns one f32x4 column-group for 8 f's.
// att staged transposed (a_t[j][f], pad 33) -> broadcast scalar reads.
// ---------------------------------------------------------------------------
__global__ __launch_bounds__(256) void k_bmix(const float* __restrict__ V,
                                              const float* __restrict__ att,
                                              float* __restrict__ bfull)
{
    __shared__ float a_t[32 * 33];
    const int tid = threadIdx.x;
    for (int i = tid; i < 1024; i += 256)
        a_t[(i & 31) * 33 + (i >> 5)] = att[i];      // a_t[j][f]
    __syncthreads();
    const int fg = blockIdx.x >> 6;                  // f-group of 8
    const int gix = (blockIdx.x & 63) * 256 + tid;   // f32x4 index over (kh,n,d)
    const f32x4* V4 = (const f32x4*)V;
    f32x4 acc[8];
#pragma unroll
    for (int q = 0; q < 8; ++q)
#pragma unroll
        for (int r = 0; r < 4; ++r) acc[q][r] = 0.f;
    for (int j = 0; j < 32; ++j) {
        f32x4 v = V4[j * 16384 + gix];
#pragma unroll
        for (int q = 0; q < 8; ++q) {
            float a = a_t[j * 33 + fg * 8 + q];
            acc[q].x += a * v.x; acc[q].y += a * v.y;
            acc[q].z += a * v.z; acc[q].w += a * v.w;
        }
    }
    f32x4* B4 = (f32x4*)bfull;
#pragma unroll
    for (int q = 0; q < 8; ++q)
        B4[(fg * 8 + q) * 16384 + gix] = acc[q];
}

// ---------------------------------------------------------------------------
// K5: per (f, 4-n tile): y1 = relu(bvec @ w3^T + b3); y = y1 @ w4^T + b4.
// w3/w4 read directly, f32x4 per-lane-row (L1 sequential). bv in padded LDS
// (4 pads per 8 keeps b128 alignment; staging writes ~2-way max).
// ---------------------------------------------------------------------------
__global__ __launch_bounds__(128) void k_out2(
    const float* __restrict__ bfull, const float* __restrict__ w3,
    const float* __restrict__ b3, const float* __restrict__ w4,
    const float* __restrict__ b4, float* __restrict__ out)
{
    const int f = blockIdx.x >> 4, nt = blockIdx.x & 15;
    __shared__ __align__(16) float bvp[4][1536];     // i_p = i + 4*(i>>3)
    __shared__ __align__(16) float y1[4][128];
    const int tid = threadIdx.x;       // 128

#pragma unroll
    for (int ni = 0; ni < 4; ++ni) {
        const int n = nt * 4 + ni;
#pragma unroll
        for (int it = 0; it < 8; ++it) {
            const int i = it * 128 + tid;            // i = d*8+kh
            const int kh = i & 7, d = i >> 3;
            bvp[ni][i + 4 * (i >> 3)] = bfull[((f * 8 + kh) * 64 + n) * 128 + d];
        }
    }
    __syncthreads();

    {   // y1: thread = dout; w3 row read f32x4 per lane (sequential, L1-hit 3/4)
        float acc[4];
        const float bias = b3[tid];
#pragma unroll
        for (int ni = 0; ni < 4; ++ni) acc[ni] = bias;
        const float* w3r = w3 + tid * 1024;
        for (int i4 = 0; i4 < 256; ++i4) {
            f32x4 w = *(const f32x4*)(w3r + i4 * 4);
            const int ip = i4 * 4 + 4 * (i4 >> 1);
#pragma unroll
            for (int ni = 0; ni < 4; ++ni) {
                f32x4 b = *(const f32x4*)(&bvp[ni][ip]);   // broadcast b128
                acc[ni] += b.x * w.x + b.y * w.y + b.z * w.z + b.w * w.w;
            }
        }
#pragma unroll
        for (int ni = 0; ni < 4; ++ni) y1[ni][tid] = fmaxf(acc[ni], 0.f);
    }
    __syncthreads();

    if (tid < 96) {                    // thread = t; w4 row f32x4 per lane
        const int t = tid;
        const float bias = b4[t];
        float s[4];
#pragma unroll
        for (int ni = 0; ni < 4; ++ni) s[ni] = bias;
        const float* w4r = w4 + t * 128;
        for (int d4 = 0; d4 < 32; ++d4) {
            f32x4 w = *(const f32x4*)(w4r + d4 * 4);
#pragma unroll
            for (int ni = 0; ni < 4; ++ni) {
                f32x4 y = *(const f32x4*)(&y1[ni][d4 * 4]);  // broadcast b128
                s[ni] += y.x * w.x + y.y * w.y + y.z * w.z + y.w * w.w;
            }
        }
#pragma unroll
        for (int ni = 0; ni < 4; ++ni) {
            const int n = nt * 4 + ni;
            out[(n * 96 + t) * 32 + f] = s[ni];
        }
    }
}

// ---------------------------------------------------------------------------
extern "C" void kernel_launch(void* const* d_in, const int* in_sizes, int n_in,
                              void* d_out, int out_size, void* d_ws, size_t ws_size,
                              hipStream_t stream)
{
    const float* x  = (const float*)d_in[0];
    const float* Wq = (const float*)d_in[1];
    const float* Wk = (const float*)d_in[2];
    const float* Wv = (const float*)d_in[3];
    const float* bq = (const float*)d_in[4];
    const float* bk = (const float*)d_in[5];
    const float* bv = (const float*)d_in[6];
    const float* w1 = (const float*)d_in[7];
    const float* b1 = (const float*)d_in[8];
    const float* w2 = (const float*)d_in[9];
    const float* b2 = (const float*)d_in[10];
    const float* w3 = (const float*)d_in[11];
    const float* b3 = (const float*)d_in[12];
    const float* w4 = (const float*)d_in[13];
    const float* b4 = (const float*)d_in[14];

    float* out = (float*)d_out;
    char*  wb  = (char*)d_ws;
    unsigned short* qhi = (unsigned short*)(wb + 0x0000000);   // 4 MB
    unsigned short* qlo = (unsigned short*)(wb + 0x0400000);   // 4 MB
    unsigned short* khi = (unsigned short*)(wb + 0x0800000);   // 4 MB
    unsigned short* klo = (unsigned short*)(wb + 0x0C00000);   // 4 MB
    float*          Vb  = (float*)        (wb + 0x1000000);    // 8 MB
    float*          Hb  = (float*)        (wb + 0x1800000);    // 32 KB
    unsigned short* Ahi = (unsigned short*)(wb + 0x1810000);   // 384 KB
    unsigned short* Alo = (unsigned short*)(wb + 0x1870000);   // 384 KB
    unsigned short* Wth = (unsigned short*)(wb + 0x18D0000);   // 576 KB
    unsigned short* Wtl = (unsigned short*)(wb + 0x1960000);   // 576 KB
    float* bfull = (float*)(wb + 0x0800000);                   // overlays khi/klo (dead after k_scores)
    float* att = out + 196608;

    k_prep  <<<88, 256, 0, stream>>>(x, Wq, Wk, Wv, Ahi, Alo, Wth, Wtl);
    k_qkvg  <<<dim3(32, 2, 24), 256, 0, stream>>>(Ahi, Alo, Wth, Wtl, bq, bk, bv,
                                                  qhi, qlo, khi, klo, Vb);
    k_scores<<<512, 256, 0, stream>>>(qhi, qlo, khi, klo, w1, Hb);
    k_soft  <<<1, 1024, 0, stream>>>(Hb, b1, w2, b2, att);
    k_bmix  <<<256, 256, 0, stream>>>(Vb, att, bfull);
    k_out2  <<<512, 128, 0, stream>>>(bfull, w3, b3, w4, b4, out);
}